// Round 10
// baseline (267.527 us; speedup 1.0000x reference)
//
#include <hip/hip_runtime.h>
#include <hip/hip_bf16.h>

#define NN 100000
#define NE 3200000
#define NF 512
#define NH 16
#define NC 40
#define BKT_SH 8
#define NBKT 391        // buckets of 256 nodes (391*256 = 100096)
#define CAP 8960        // max edges/bucket (mean 8192, sigma ~91, +8.5 sigma)
#define HISTB 1536      // hist rows (blocks doing hist inside kA)
#define CHUNK_H 2084    // edges per hist row (1536*2084 = 3201024 >= NE)
#define SCATB 256       // scatter blocks
#define CHUNK_S 12504   // edges per scatter block (6*2084)
#define GEMMB 1563      // ceil(NN/64)

typedef __attribute__((ext_vector_type(4))) float f32x4;
typedef __attribute__((ext_vector_type(8))) short bf16x8;

static __device__ __forceinline__ unsigned short f2b(float f) {
    unsigned int u = __float_as_uint(f);
    u += 0x7FFFu + ((u >> 16) & 1u);   // round-to-nearest-even
    return (unsigned short)(u >> 16);
}
static __device__ __forceinline__ float b2f(unsigned short u) {
    return __uint_as_float(((unsigned int)u) << 16);
}

// ---------------- fused: every block a GEMM tile; blocks<HISTB do a small hist slice first --
// gemm with 8-deep register prefetch: ~256B/lane in flight (the round-6 kA was
// loads-in-flight-bound at ~1.6TB/s; this raises in-flight ~4x)

__global__ void __launch_bounds__(256) kA_gemm_hist(const float* __restrict__ x,
                                                    const float* __restrict__ W1,
                                                    const int* __restrict__ ei,
                                                    unsigned short* __restrict__ h1,
                                                    int* __restrict__ histG,
                                                    int* __restrict__ done) {
    __shared__ int smem[4096];   // 16KB: hist h[NBKT] first, then packed W1 (8192 bf16)
    int tid = threadIdx.x;
    if (blockIdx.x == 0 && tid == 0) *done = 0;   // reset colscan ticket each call
    if (blockIdx.x < HISTB) {    // ~8 iterations: amortized under gemm
        int* h = smem;
        for (int i = tid; i < NBKT; i += 256) h[i] = 0;
        __syncthreads();
        int r = blockIdx.x;
        int e0 = r * CHUNK_H, e1 = min(NE, e0 + CHUNK_H);
        for (int e = e0 + tid; e < e1; e += 256)
            atomicAdd(&h[((unsigned)ei[NE + e]) >> BKT_SH], 1);
        __syncthreads();
        for (int i = tid; i < NBKT; i += 256)
            histG[r * NBKT + i] = h[i];
        __syncthreads();
    }
    // ---- pack W1 into LDS (fragment layout) ----
    unsigned short* wl = (unsigned short*)smem;
    for (int idx = tid; idx < 8192; idx += 256) {
        int s = idx >> 9;
        int l = (idx >> 3) & 63;
        int e = idx & 7;
        int k = s * 32 + (l >> 4) * 8 + e;
        wl[idx] = f2b(W1[k * 16 + (l & 15)]);
    }
    __syncthreads();
    int wave = tid >> 6;
    int l = tid & 63;
    int m0 = blockIdx.x * 64 + wave * 16;
    if (m0 >= NN) return;
    int row = m0 + (l & 15);
    int krow = (l >> 4) * 8;
    const float* xr = x + (size_t)row * NF + krow;
    const unsigned short* wf = wl + l * 8;

    f32x4 xa[8], xb[8];
#pragma unroll
    for (int s = 0; s < 8; ++s) {           // 16 loads (256B/lane) issued up front
        xa[s] = *(const f32x4*)(xr + s * 32);
        xb[s] = *(const f32x4*)(xr + s * 32 + 4);
    }
    f32x4 acc = {0.f, 0.f, 0.f, 0.f};
#pragma unroll
    for (int s = 0; s < 8; ++s) {           // consume s, prefetch s+8
        f32x4 na = *(const f32x4*)(xr + (s + 8) * 32);
        f32x4 nb = *(const f32x4*)(xr + (s + 8) * 32 + 4);
        union { bf16x8 v; unsigned short u[8]; } a;
        a.u[0] = f2b(xa[s].x); a.u[1] = f2b(xa[s].y); a.u[2] = f2b(xa[s].z); a.u[3] = f2b(xa[s].w);
        a.u[4] = f2b(xb[s].x); a.u[5] = f2b(xb[s].y); a.u[6] = f2b(xb[s].z); a.u[7] = f2b(xb[s].w);
        bf16x8 b = *(const bf16x8*)(wf + s * 512);
        acc = __builtin_amdgcn_mfma_f32_16x16x32_bf16(a.v, b, acc, 0, 0, 0);
        xa[s] = na; xb[s] = nb;
    }
#pragma unroll
    for (int s = 0; s < 8; ++s) {           // drain
        union { bf16x8 v; unsigned short u[8]; } a;
        a.u[0] = f2b(xa[s].x); a.u[1] = f2b(xa[s].y); a.u[2] = f2b(xa[s].z); a.u[3] = f2b(xa[s].w);
        a.u[4] = f2b(xb[s].x); a.u[5] = f2b(xb[s].y); a.u[6] = f2b(xb[s].z); a.u[7] = f2b(xb[s].w);
        bf16x8 b = *(const bf16x8*)(wf + (s + 8) * 512);
        acc = __builtin_amdgcn_mfma_f32_16x16x32_bf16(a.v, b, acc, 0, 0, 0);
    }
    // C layout: col = l&15, row = (l>>4)*4 + r
#pragma unroll
    for (int r = 0; r < 4; ++r) {
        int orow = m0 + (l >> 4) * 4 + r;
        h1[(size_t)orow * NH + (l & 15)] = f2b(acc[r]);
    }
}

// ---------------- per-bucket scan over hist rows; last block also scans bucket totals -------

__global__ void __launch_bounds__(512) k_colscan(const int* __restrict__ histG,
                                                 int* __restrict__ ofsG,
                                                 int* __restrict__ bcnt,
                                                 int* __restrict__ bptr,
                                                 int* __restrict__ rowptr,
                                                 int* __restrict__ done) {
    __shared__ int sh[512];
    __shared__ int isLast;
    int k = blockIdx.x;
    int t = threadIdx.x;
    int base = t * 3;
    int a0 = histG[(size_t)(base + 0) * NBKT + k];
    int a1 = histG[(size_t)(base + 1) * NBKT + k];
    int a2 = histG[(size_t)(base + 2) * NBKT + k];
    int s = a0 + a1 + a2;
    sh[t] = s;
    __syncthreads();
    for (int off = 1; off < 512; off <<= 1) {
        int add = (t >= off) ? sh[t - off] : 0;
        __syncthreads();
        sh[t] += add;
        __syncthreads();
    }
    int excl = sh[t] - s;
    if ((t & 1) == 0) ofsG[(size_t)k * SCATB + (t >> 1)] = excl;  // row 6b boundary
    if (t == 511) bcnt[k] = sh[t];
    // ---- last finishing block runs the bucket-total scan ----
    __threadfence();
    __syncthreads();
    if (t == 0) isLast = (atomicAdd(done, 1) == NBKT - 1);
    __syncthreads();
    if (!isLast) return;
    int v = (t < NBKT) ? bcnt[t] : 0;
    __syncthreads();
    sh[t] = v;
    __syncthreads();
    for (int off = 1; off < 512; off <<= 1) {
        int add = (t >= off) ? sh[t - off] : 0;
        __syncthreads();
        sh[t] += add;
        __syncthreads();
    }
    if (t < NBKT) bptr[t] = sh[t] - v;
    if (t == 0) { bptr[NBKT] = NE; rowptr[NN] = NE; }
}

// ---------------- scatter via LDS cursors; 128B avg segments per (block,bucket) ------------

__global__ void __launch_bounds__(1024) k_msscatter(const int* __restrict__ ei,
                                                    const int* __restrict__ bptr,
                                                    const int* __restrict__ ofsG,
                                                    unsigned int* __restrict__ pairs) {
    __shared__ int lcur[NBKT];
    int b = blockIdx.x;
    for (int k = threadIdx.x; k < NBKT; k += 1024)
        lcur[k] = bptr[k] + ofsG[(size_t)k * SCATB + b];
    __syncthreads();
    int e0 = b * CHUNK_S, e1 = min(NE, e0 + CHUNK_S);
    for (int e = e0 + threadIdx.x; e < e1; e += 1024) {
        unsigned int s = (unsigned int)ei[e];
        unsigned int d = (unsigned int)ei[NE + e];
        int pos = atomicAdd(&lcur[d >> BKT_SH], 1);
        pairs[pos] = s | ((d & 255u) << 17);
    }
}

// ---------------- per-bucket (256 nodes) counting sort -> CSR; 1024 thr ----------

__global__ void __launch_bounds__(1024) k_bsort(const unsigned int* __restrict__ pairs,
                                                const int* __restrict__ bptr,
                                                int* __restrict__ rowptr,
                                                float* __restrict__ dinv,
                                                int* __restrict__ ssrc) {
    __shared__ unsigned int ein[CAP];
    __shared__ unsigned int srt[CAP];
    __shared__ int lcnt[256], lofs[256], lcur[256];
    int b = blockIdx.x;
    int t = threadIdx.x;
    int s0 = bptr[b], s1 = bptr[b + 1];
    int n = s1 - s0;
    for (int i = t; i < n; i += 1024) ein[i] = pairs[s0 + i];
    if (t < 256) lcnt[t] = 0;
    __syncthreads();
    for (int i = t; i < n; i += 1024) atomicAdd(&lcnt[ein[i] >> 17], 1);
    __syncthreads();
    if (t < 256) lofs[t] = lcnt[t];
    __syncthreads();
    for (int off = 1; off < 256; off <<= 1) {
        int add = 0;
        if (t < 256 && t >= off) add = lofs[t - off];
        __syncthreads();
        if (t < 256) lofs[t] += add;
        __syncthreads();
    }
    if (t < 256) {
        int excl = lofs[t] - lcnt[t];
        lcur[t] = excl;
        int node = b * 256 + t;
        if (node < NN) {
            rowptr[node] = s0 + excl;
            dinv[node] = rsqrtf((float)(lcnt[t] + 1));
        }
    }
    __syncthreads();
    for (int i = t; i < n; i += 1024) {
        unsigned int v = ein[i];
        int pos = atomicAdd(&lcur[v >> 17], 1);
        srt[pos] = v & 0x1FFFFu;
    }
    __syncthreads();
    for (int i = t; i < n; i += 1024) ssrc[s0 + i] = (int)srt[i];
}

// ---------------- layer-1 aggregation: one wave per node (round-8 form) ----------------
// h1 unscaled: acc = h1[node]*di + sum h1[src]*dinv[src];  r1 = bf16(relu(acc*di+b1)*di)

__global__ void __launch_bounds__(256) k_agg1(const unsigned short* __restrict__ hs,
                                              const int* __restrict__ rowptr,
                                              const int* __restrict__ ssrc,
                                              const float* __restrict__ dinv,
                                              const float* __restrict__ b1,
                                              unsigned short* __restrict__ r1) {
    int l = threadIdx.x & 63;
    int node = blockIdx.x * 4 + (threadIdx.x >> 6);
    int j = l & 15;
    int ec = l >> 4;
    float di = dinv[node];
    int s = rowptr[node];
    int e1 = rowptr[node + 1];
    float acc = (ec == 0) ? b2f(hs[(size_t)node * NH + j]) * di : 0.0f;
#pragma unroll 4
    for (int e = s + ec; e < e1; e += 4) {
        int src = ssrc[e];
        acc += b2f(hs[(size_t)src * NH + j]) * dinv[src];
    }
    acc += __shfl_xor(acc, 16, 64);
    acc += __shfl_xor(acc, 32, 64);
    if (ec == 0) {
        float o = fmaxf(acc * di + b1[j], 0.0f) * di;
        r1[(size_t)node * NH + j] = f2b(o);
    }
}

// ---------------- layer-2 aggregation + classifier + log_softmax (round-8 form) ------------

__global__ void __launch_bounds__(256) k_agg2(const unsigned short* __restrict__ rs,
                                              const int* __restrict__ rowptr,
                                              const int* __restrict__ ssrc,
                                              const float* __restrict__ dinv,
                                              const float* __restrict__ W2,
                                              const float* __restrict__ b2,
                                              float* __restrict__ out) {
    __shared__ float w[NH * NC];
    __shared__ float bb[NC];
    int t = threadIdx.x;
    for (int i = t; i < NH * NC; i += 256) w[i] = W2[i];
    if (t < NC) bb[t] = b2[t];
    __syncthreads();
    int l = t & 63;
    int node = blockIdx.x * 4 + (t >> 6);
    int j = l & 15;
    int ec = l >> 4;
    float di = dinv[node];
    int s = rowptr[node];
    int e1 = rowptr[node + 1];
    float acc = (ec == 0) ? b2f(rs[(size_t)node * NH + j]) : 0.0f;
#pragma unroll 4
    for (int e = s + ec; e < e1; e += 4) {
        int src = ssrc[e];
        acc += b2f(rs[(size_t)src * NH + j]);
    }
    acc += __shfl_xor(acc, 16, 64);
    acc += __shfl_xor(acc, 32, 64);
    float zv = acc * di;
    float lg = (l < NC) ? bb[l] : -1e30f;
#pragma unroll
    for (int k = 0; k < NH; ++k) {
        float zk = __shfl(zv, k, 64);
        if (l < NC) lg += zk * w[k * NC + l];
    }
    float mx = lg;
#pragma unroll
    for (int off = 1; off < 64; off <<= 1) mx = fmaxf(mx, __shfl_xor(mx, off, 64));
    float ex = (l < NC) ? __expf(lg - mx) : 0.0f;
    float sm = ex;
#pragma unroll
    for (int off = 1; off < 64; off <<= 1) sm += __shfl_xor(sm, off, 64);
    if (l < NC) out[(size_t)node * NC + l] = lg - mx - __logf(sm);
}

// ---------------- launch ----------------

extern "C" void kernel_launch(void* const* d_in, const int* in_sizes, int n_in,
                              void* d_out, int out_size, void* d_ws, size_t ws_size,
                              hipStream_t stream) {
    const float* x  = (const float*)d_in[0];
    const int*   ei = (const int*)d_in[1];
    const float* W1 = (const float*)d_in[2];
    const float* b1 = (const float*)d_in[3];
    const float* W2 = (const float*)d_in[4];
    const float* b2 = (const float*)d_in[5];
    float* out = (float*)d_out;

    char* ws = (char*)d_ws;
    size_t off = 0;
    auto alloc = [&](size_t bytes) -> void* {
        void* p = ws + off;
        off += (bytes + 255) & ~(size_t)255;
        return p;
    };
    int* histG      = (int*)alloc((size_t)HISTB * NBKT * 4);     // 2.4 MB
    int* ofsG       = (int*)alloc((size_t)NBKT * SCATB * 4);     // 400 KB
    int* bcnt       = (int*)alloc((size_t)NBKT * 4);
    int* bptr       = (int*)alloc((size_t)(NBKT + 1) * 4);
    int* rowptr     = (int*)alloc((size_t)(NN + 1) * 4);
    float* dinv     = (float*)alloc((size_t)NN * 4);
    int* done       = (int*)alloc(256);
    unsigned int* pairs = (unsigned int*)alloc((size_t)NE * 4);
    int* ssrc       = (int*)alloc((size_t)NE * 4);
    unsigned short* h1  = (unsigned short*)alloc((size_t)NN * NH * 2);  // bf16, unscaled
    unsigned short* r1  = (unsigned short*)alloc((size_t)NN * NH * 2);  // bf16, pre-scaled

    kA_gemm_hist<<<GEMMB, 256, 0, stream>>>(x, W1, ei, h1, histG, done);
    k_colscan<<<NBKT, 512, 0, stream>>>(histG, ofsG, bcnt, bptr, rowptr, done);
    k_msscatter<<<SCATB, 1024, 0, stream>>>(ei, bptr, ofsG, pairs);
    k_bsort<<<NBKT, 1024, 0, stream>>>(pairs, bptr, rowptr, dinv, ssrc);
    k_agg1<<<NN / 4, 256, 0, stream>>>(h1, rowptr, ssrc, dinv, b1, r1);
    k_agg2<<<NN / 4, 256, 0, stream>>>(r1, rowptr, ssrc, dinv, W2, b2, out);
}

// Round 11
// 224.569 us; speedup vs baseline: 1.1913x; 1.1913x over previous
//
#include <hip/hip_runtime.h>
#include <hip/hip_bf16.h>

#define NN 100000
#define NE 3200000
#define NF 512
#define NH 16
#define NC 40
#define BKT_SH 8
#define NBKT 391        // buckets of 256 nodes (391*256 = 100096)
#define CAP 8960        // max edges/bucket (mean 8192, sigma ~91, +8.5 sigma)
#define HISTB 1536      // hist rows (blocks doing hist inside kA)
#define CHUNK_H 2084    // edges per hist row (1536*2084 = 3201024 >= NE)
#define SCATB 256       // scatter blocks
#define CHUNK_S 12504   // edges per scatter block (6*2084)
#define GEMMB 1563      // ceil(NN/64)
#define KC 64           // f32 per K-chunk
#define NCHUNK 8        // 512/64

typedef __attribute__((ext_vector_type(4))) float f32x4;
typedef __attribute__((ext_vector_type(8))) short bf16x8;

static __device__ __forceinline__ unsigned short f2b(float f) {
    unsigned int u = __float_as_uint(f);
    u += 0x7FFFu + ((u >> 16) & 1u);   // round-to-nearest-even
    return (unsigned short)(u >> 16);
}
static __device__ __forceinline__ float b2f(unsigned short u) {
    return __uint_as_float(((unsigned int)u) << 16);
}

// ---------------- fused: every block a GEMM tile; blocks<HISTB do a small hist slice first --
// GEMM: X staged via global_load_lds (dbuf 2x16KB) -> zero VGPR cost, deep vmcnt queue.
// LDS X layout XOR-swizzled (colbyte ^= (row&7)<<5); inverse swizzle applied on the
// GLOBAL source address (global_load_lds dest is linear: base + lane*16).

__global__ void __launch_bounds__(256) kA_gemm_hist(const float* __restrict__ x,
                                                    const float* __restrict__ W1,
                                                    const int* __restrict__ ei,
                                                    unsigned short* __restrict__ h1,
                                                    int* __restrict__ histG) {
    __shared__ char smem[49152];   // [0,16K): hist then packed W1; [16K,48K): X dbuf
    int tid = threadIdx.x;
    if (blockIdx.x < HISTB) {      // ~8 iterations: amortized under gemm
        int* h = (int*)smem;
        for (int i = tid; i < NBKT; i += 256) h[i] = 0;
        __syncthreads();
        int r = blockIdx.x;
        int e0 = r * CHUNK_H, e1 = min(NE, e0 + CHUNK_H);
        for (int e = e0 + tid; e < e1; e += 256)
            atomicAdd(&h[((unsigned)ei[NE + e]) >> BKT_SH], 1);
        __syncthreads();
        for (int i = tid; i < NBKT; i += 256)
            histG[r * NBKT + i] = h[i];
        __syncthreads();
    }
    // ---- pack W1 into LDS (fragment layout) ----
    unsigned short* wl = (unsigned short*)smem;
    for (int idx = tid; idx < 8192; idx += 256) {
        int s = idx >> 9;
        int l = (idx >> 3) & 63;
        int e = idx & 7;
        int k = s * 32 + (l >> 4) * 8 + e;
        wl[idx] = f2b(W1[k * 16 + (l & 15)]);
    }
    float* xbuf = (float*)(smem + 16384);   // 2 x 4096 f32
    int w = tid >> 6;
    int l = tid & 63;
    int m0row = blockIdx.x * 64;
    int srow = tid >> 4;          // staging row (+ t*16)
    int sunit = tid & 15;         // staging 16B unit within row

    auto stage = [&](int buf, int c) {
        float* dst = xbuf + buf * 4096;
        int kb = c * KC;
#pragma unroll
        for (int t = 0; t < 4; ++t) {
            int row = t * 16 + srow;
            int grow = m0row + row;
            if (grow >= NN) grow = NN - 1;             // clamp tail reads
            int colbyte = (sunit * 16) ^ ((row & 7) << 5);   // inverse swizzle on source
            const float* g = x + (size_t)grow * NF + kb + (colbyte >> 2);
            float* ldsb = dst + t * 1024 + w * 256;    // wave-uniform; HW adds lane*16
            __builtin_amdgcn_global_load_lds(
                (const __attribute__((address_space(1))) void*)g,
                (__attribute__((address_space(3))) void*)ldsb, 16, 0, 0);
        }
    };

    int rowl = w * 16 + (l & 15);   // A-fragment row (local)
    int hq = l >> 4;
    int rbase = rowl * 64;          // f32 index of row start in tile
    f32x4 acc = {0.f, 0.f, 0.f, 0.f};

    stage(0, 0);
    __syncthreads();                 // also covers W1-pack LDS writes
    for (int c = 0; c < NCHUNK; ++c) {
        if (c + 1 < NCHUNK) stage((c + 1) & 1, c + 1);
        const float* src = xbuf + (c & 1) * 4096;
#pragma unroll
        for (int sl = 0; sl < 2; ++sl) {
            int colbyte = (sl * 128 + hq * 32) ^ ((rowl & 7) << 5);  // swizzled read
            const float* p = src + rbase + (colbyte >> 2);
            f32x4 xa = *(const f32x4*)p;
            f32x4 xb = *(const f32x4*)(p + 4);
            union { bf16x8 v; unsigned short u[8]; } a;
            a.u[0] = f2b(xa.x); a.u[1] = f2b(xa.y); a.u[2] = f2b(xa.z); a.u[3] = f2b(xa.w);
            a.u[4] = f2b(xb.x); a.u[5] = f2b(xb.y); a.u[6] = f2b(xb.z); a.u[7] = f2b(xb.w);
            bf16x8 b = *(const bf16x8*)(wl + l * 8 + (c * 2 + sl) * 512);
            acc = __builtin_amdgcn_mfma_f32_16x16x32_bf16(a.v, b, acc, 0, 0, 0);
        }
        __syncthreads();
    }
    if (m0row + w * 16 < NN) {      // NN%16==0: whole wave tile valid or invalid
        // C layout: col = l&15, row = hq*4 + r
#pragma unroll
        for (int r = 0; r < 4; ++r) {
            int orow = m0row + w * 16 + hq * 4 + r;
            h1[(size_t)orow * NH + (l & 15)] = f2b(acc[r]);
        }
    }
}

// ---------------- per-bucket scan over the 1536 hist rows (3 rows/thread) ----------------
// emits ofsG[k][b] = prefix at row 6b, and bcnt[k] = column total

__global__ void __launch_bounds__(512) k_colscan(const int* __restrict__ histG,
                                                 int* __restrict__ ofsG,
                                                 int* __restrict__ bcnt) {
    __shared__ int sh[512];
    int k = blockIdx.x;
    int t = threadIdx.x;
    int base = t * 3;
    int a0 = histG[(size_t)(base + 0) * NBKT + k];
    int a1 = histG[(size_t)(base + 1) * NBKT + k];
    int a2 = histG[(size_t)(base + 2) * NBKT + k];
    int s = a0 + a1 + a2;
    sh[t] = s;
    __syncthreads();
    for (int off = 1; off < 512; off <<= 1) {
        int add = (t >= off) ? sh[t - off] : 0;
        __syncthreads();
        sh[t] += add;
        __syncthreads();
    }
    int excl = sh[t] - s;
    if ((t & 1) == 0) ofsG[(size_t)k * SCATB + (t >> 1)] = excl;  // row 6b boundary
    if (t == 511) bcnt[k] = sh[t];
}

// ---------------- scan bucket totals (391) ----------------

__global__ void k_bscan(const int* __restrict__ bcnt, int* __restrict__ bptr,
                        int* __restrict__ rowptr) {
    __shared__ int sh[512];
    int t = threadIdx.x;
    int v = (t < NBKT) ? bcnt[t] : 0;
    sh[t] = v;
    __syncthreads();
    for (int off = 1; off < 512; off <<= 1) {
        int add = (t >= off) ? sh[t - off] : 0;
        __syncthreads();
        sh[t] += add;
        __syncthreads();
    }
    if (t < NBKT) bptr[t] = sh[t] - v;
    if (t == 0) { bptr[NBKT] = NE; rowptr[NN] = NE; }
}

// ---------------- scatter via LDS cursors; 128B avg segments per (block,bucket) ------------

__global__ void __launch_bounds__(1024) k_msscatter(const int* __restrict__ ei,
                                                    const int* __restrict__ bptr,
                                                    const int* __restrict__ ofsG,
                                                    unsigned int* __restrict__ pairs) {
    __shared__ int lcur[NBKT];
    int b = blockIdx.x;
    for (int k = threadIdx.x; k < NBKT; k += 1024)
        lcur[k] = bptr[k] + ofsG[(size_t)k * SCATB + b];
    __syncthreads();
    int e0 = b * CHUNK_S, e1 = min(NE, e0 + CHUNK_S);
    for (int e = e0 + threadIdx.x; e < e1; e += 1024) {
        unsigned int s = (unsigned int)ei[e];
        unsigned int d = (unsigned int)ei[NE + e];
        int pos = atomicAdd(&lcur[d >> BKT_SH], 1);
        pairs[pos] = s | ((d & 255u) << 17);
    }
}

// ---------------- per-bucket (256 nodes) counting sort -> CSR; 1024 thr ----------

__global__ void __launch_bounds__(1024) k_bsort(const unsigned int* __restrict__ pairs,
                                                const int* __restrict__ bptr,
                                                int* __restrict__ rowptr,
                                                float* __restrict__ dinv,
                                                int* __restrict__ ssrc) {
    __shared__ unsigned int ein[CAP];
    __shared__ unsigned int srt[CAP];
    __shared__ int lcnt[256], lofs[256], lcur[256];
    int b = blockIdx.x;
    int t = threadIdx.x;
    int s0 = bptr[b], s1 = bptr[b + 1];
    int n = s1 - s0;
    for (int i = t; i < n; i += 1024) ein[i] = pairs[s0 + i];
    if (t < 256) lcnt[t] = 0;
    __syncthreads();
    for (int i = t; i < n; i += 1024) atomicAdd(&lcnt[ein[i] >> 17], 1);
    __syncthreads();
    if (t < 256) lofs[t] = lcnt[t];
    __syncthreads();
    for (int off = 1; off < 256; off <<= 1) {
        int add = 0;
        if (t < 256 && t >= off) add = lofs[t - off];
        __syncthreads();
        if (t < 256) lofs[t] += add;
        __syncthreads();
    }
    if (t < 256) {
        int excl = lofs[t] - lcnt[t];
        lcur[t] = excl;
        int node = b * 256 + t;
        if (node < NN) {
            rowptr[node] = s0 + excl;
            dinv[node] = rsqrtf((float)(lcnt[t] + 1));
        }
    }
    __syncthreads();
    for (int i = t; i < n; i += 1024) {
        unsigned int v = ein[i];
        int pos = atomicAdd(&lcur[v >> 17], 1);
        srt[pos] = v & 0x1FFFFu;
    }
    __syncthreads();
    for (int i = t; i < n; i += 1024) ssrc[s0 + i] = (int)srt[i];
}

// ---------------- layer-1 aggregation: one wave per node (round-8 form) ----------------
// h1 unscaled: acc = h1[node]*di + sum h1[src]*dinv[src];  r1 = bf16(relu(acc*di+b1)*di)

__global__ void __launch_bounds__(256) k_agg1(const unsigned short* __restrict__ hs,
                                              const int* __restrict__ rowptr,
                                              const int* __restrict__ ssrc,
                                              const float* __restrict__ dinv,
                                              const float* __restrict__ b1,
                                              unsigned short* __restrict__ r1) {
    int l = threadIdx.x & 63;
    int node = blockIdx.x * 4 + (threadIdx.x >> 6);
    int j = l & 15;
    int ec = l >> 4;
    float di = dinv[node];
    int s = rowptr[node];
    int e1 = rowptr[node + 1];
    float acc = (ec == 0) ? b2f(hs[(size_t)node * NH + j]) * di : 0.0f;
#pragma unroll 4
    for (int e = s + ec; e < e1; e += 4) {
        int src = ssrc[e];
        acc += b2f(hs[(size_t)src * NH + j]) * dinv[src];
    }
    acc += __shfl_xor(acc, 16, 64);
    acc += __shfl_xor(acc, 32, 64);
    if (ec == 0) {
        float o = fmaxf(acc * di + b1[j], 0.0f) * di;
        r1[(size_t)node * NH + j] = f2b(o);
    }
}

// ---------------- layer-2 aggregation + classifier + log_softmax (round-8 form) ------------

__global__ void __launch_bounds__(256) k_agg2(const unsigned short* __restrict__ rs,
                                              const int* __restrict__ rowptr,
                                              const int* __restrict__ ssrc,
                                              const float* __restrict__ dinv,
                                              const float* __restrict__ W2,
                                              const float* __restrict__ b2,
                                              float* __restrict__ out) {
    __shared__ float w[NH * NC];
    __shared__ float bb[NC];
    int t = threadIdx.x;
    for (int i = t; i < NH * NC; i += 256) w[i] = W2[i];
    if (t < NC) bb[t] = b2[t];
    __syncthreads();
    int l = t & 63;
    int node = blockIdx.x * 4 + (t >> 6);
    int j = l & 15;
    int ec = l >> 4;
    float di = dinv[node];
    int s = rowptr[node];
    int e1 = rowptr[node + 1];
    float acc = (ec == 0) ? b2f(rs[(size_t)node * NH + j]) : 0.0f;
#pragma unroll 4
    for (int e = s + ec; e < e1; e += 4) {
        int src = ssrc[e];
        acc += b2f(rs[(size_t)src * NH + j]);
    }
    acc += __shfl_xor(acc, 16, 64);
    acc += __shfl_xor(acc, 32, 64);
    float zv = acc * di;
    float lg = (l < NC) ? bb[l] : -1e30f;
#pragma unroll
    for (int k = 0; k < NH; ++k) {
        float zk = __shfl(zv, k, 64);
        if (l < NC) lg += zk * w[k * NC + l];
    }
    float mx = lg;
#pragma unroll
    for (int off = 1; off < 64; off <<= 1) mx = fmaxf(mx, __shfl_xor(mx, off, 64));
    float ex = (l < NC) ? __expf(lg - mx) : 0.0f;
    float sm = ex;
#pragma unroll
    for (int off = 1; off < 64; off <<= 1) sm += __shfl_xor(sm, off, 64);
    if (l < NC) out[(size_t)node * NC + l] = lg - mx - __logf(sm);
}

// ---------------- launch ----------------

extern "C" void kernel_launch(void* const* d_in, const int* in_sizes, int n_in,
                              void* d_out, int out_size, void* d_ws, size_t ws_size,
                              hipStream_t stream) {
    const float* x  = (const float*)d_in[0];
    const int*   ei = (const int*)d_in[1];
    const float* W1 = (const float*)d_in[2];
    const float* b1 = (const float*)d_in[3];
    const float* W2 = (const float*)d_in[4];
    const float* b2 = (const float*)d_in[5];
    float* out = (float*)d_out;

    char* ws = (char*)d_ws;
    size_t off = 0;
    auto alloc = [&](size_t bytes) -> void* {
        void* p = ws + off;
        off += (bytes + 255) & ~(size_t)255;
        return p;
    };
    int* histG      = (int*)alloc((size_t)HISTB * NBKT * 4);     // 2.4 MB
    int* ofsG       = (int*)alloc((size_t)NBKT * SCATB * 4);     // 400 KB
    int* bcnt       = (int*)alloc((size_t)NBKT * 4);
    int* bptr       = (int*)alloc((size_t)(NBKT + 1) * 4);
    int* rowptr     = (int*)alloc((size_t)(NN + 1) * 4);
    float* dinv     = (float*)alloc((size_t)NN * 4);
    unsigned int* pairs = (unsigned int*)alloc((size_t)NE * 4);
    int* ssrc       = (int*)alloc((size_t)NE * 4);
    unsigned short* h1  = (unsigned short*)alloc((size_t)NN * NH * 2);  // bf16, unscaled
    unsigned short* r1  = (unsigned short*)alloc((size_t)NN * NH * 2);  // bf16, pre-scaled

    kA_gemm_hist<<<GEMMB, 256, 0, stream>>>(x, W1, ei, h1, histG);
    k_colscan<<<NBKT, 512, 0, stream>>>(histG, ofsG, bcnt);
    k_bscan<<<1, 512, 0, stream>>>(bcnt, bptr, rowptr);
    k_msscatter<<<SCATB, 1024, 0, stream>>>(ei, bptr, ofsG, pairs);
    k_bsort<<<NBKT, 1024, 0, stream>>>(pairs, bptr, rowptr, dinv, ssrc);
    k_agg1<<<NN / 4, 256, 0, stream>>>(h1, rowptr, ssrc, dinv, b1, r1);
    k_agg2<<<NN / 4, 256, 0, stream>>>(r1, rowptr, ssrc, dinv, W2, b2, out);
}